// Round 1
// baseline (400.131 us; speedup 1.0000x reference)
//
#include <hip/hip_runtime.h>
#include <math.h>

#define NW     10
#define DIM    1024
#define QDEPTH 16

// ws layout:
//   [0, 1280) floats : 160 gate matrices (l*10+w), 8 floats each:
//                      m00.re, m00.im, m01.re, m01.im, m10.re, m10.im, m11.re, m11.im
//   at byte 5120     : int iperm[16][1024]  (per-layer CNOT-block gather table)

__device__ inline void gate2(const float* __restrict__ g, float2& p0, float2& p1) {
    // new0 = m00*p0 + m01*p1 ; new1 = m10*p0 + m11*p1   (complex)
    float m00r = g[0], m00i = g[1], m01r = g[2], m01i = g[3];
    float m10r = g[4], m10i = g[5], m11r = g[6], m11i = g[7];
    float n0x = m00r*p0.x - m00i*p0.y + m01r*p1.x - m01i*p1.y;
    float n0y = m00r*p0.y + m00i*p0.x + m01r*p1.y + m01i*p1.x;
    float n1x = m10r*p0.x - m10i*p0.y + m11r*p1.x - m11i*p1.y;
    float n1y = m10r*p0.y + m10i*p0.x + m11r*p1.y + m11i*p1.x;
    p0 = make_float2(n0x, n0y);
    p1 = make_float2(n1x, n1y);
}

__global__ __launch_bounds__(1024)
void prep_kernel(const float* __restrict__ w, float* __restrict__ gates,
                 int* __restrict__ iperm) {
    int t = threadIdx.x;  // 1024 threads, 1 block
    const float PI = 3.14159265358979323846f;
    if (t < QDEPTH * NW) {
        // Rot(phi, theta, omega) = RZ(omega) RY(theta) RZ(phi); angles = tanh(w)*pi
        float phi   = tanhf(w[t*3 + 0]) * PI;
        float theta = tanhf(w[t*3 + 1]) * PI;
        float omega = tanhf(w[t*3 + 2]) * PI;
        float ch = cosf(theta * 0.5f), sh = sinf(theta * 0.5f);
        float ap = (phi + omega) * 0.5f;   // m00 = e^{-i ap} c, m11 = e^{i ap} c
        float am = (phi - omega) * 0.5f;   // m01 = -e^{i am} s, m10 = e^{-i am} s
        float* g = gates + t * 8;
        g[0] =  cosf(ap) * ch;  g[1] = -sinf(ap) * ch;   // m00
        g[2] = -cosf(am) * sh;  g[3] = -sinf(am) * sh;   // m01
        g[4] =  cosf(am) * sh;  g[5] = -sinf(am) * sh;   // m10
        g[6] =  cosf(ap) * ch;  g[7] =  sinf(ap) * ch;   // m11
    }
    // Per-layer CNOT block as a gather permutation.
    // state_{k}[v] = state_{k-1}[g_k(v)], g_k(v) = v ^ ((v>>bc)&1)<<bt.
    // Composition over w=0..9 applied in order => gather index G(v) = g_0(g_1(...g_9(v))).
    int v = t;
    for (int l = 0; l < QDEPTH; ++l) {
        int r = (l % (NW - 1)) + 1;
        int u = v;
        for (int wq = NW - 1; wq >= 0; --wq) {
            int bc = 9 - wq;
            int bt = 9 - ((wq + r) % NW);
            u ^= ((u >> bc) & 1) << bt;
        }
        iperm[l * DIM + v] = u;
    }
}

__global__ __launch_bounds__(256)
void sim_kernel(const float* __restrict__ x, const float* __restrict__ gates,
                const int* __restrict__ iperm, float* __restrict__ out) {
    __shared__ float2 st[DIM];
    __shared__ float red[4];
    const int n = blockIdx.x;
    const int t = threadIdx.x;

    // ---- load + normalize (AmplitudeEmbedding, normalize=True) ----
    const float* xr = x + (size_t)n * DIM;
    float v0 = xr[t], v1 = xr[t + 256], v2 = xr[t + 512], v3 = xr[t + 768];
    float ss = v0*v0 + v1*v1 + v2*v2 + v3*v3;
    #pragma unroll
    for (int o = 32; o >= 1; o >>= 1) ss += __shfl_down(ss, o, 64);
    if ((t & 63) == 0) red[t >> 6] = ss;
    __syncthreads();
    float inv = rsqrtf(red[0] + red[1] + red[2] + red[3]);
    st[t]       = make_float2(v0 * inv, 0.f);
    st[t + 256] = make_float2(v1 * inv, 0.f);
    st[t + 512] = make_float2(v2 * inv, 0.f);
    st[t + 768] = make_float2(v3 * inv, 0.f);
    __syncthreads();

    // ---- 16 layers ----
    for (int l = 0; l < QDEPTH; ++l) {
        const float* gl = gates + l * NW * 8;
        // 5 fused-Rot passes over bit pairs (9,8),(7,6),(5,4),(3,2),(1,0).
        // wire w <-> bit 9-w; Rots within a layer commute.
        #pragma unroll
        for (int pb = 4; pb >= 0; --pb) {
            const int b = 2 * pb;                   // low bit of the pair
            const float* gh = gl + (8 - b) * 8;     // gate on bit b+1 (wire 8-b)
            const float* gm = gl + (9 - b) * 8;     // gate on bit b   (wire 9-b)
            const int low = t & ((1 << b) - 1);
            const int i00 = ((t >> b) << (b + 2)) | low;
            const int i01 = i00 | (1 << b);
            const int i10 = i00 | (2 << b);
            const int i11 = i00 | (3 << b);
            float2 a00 = st[i00], a01 = st[i01], a10 = st[i10], a11 = st[i11];
            // gate on hi bit: pairs (a00,a10), (a01,a11)
            gate2(gh, a00, a10);
            gate2(gh, a01, a11);
            // gate on lo bit: pairs (a00,a01), (a10,a11)
            gate2(gm, a00, a01);
            gate2(gm, a10, a11);
            st[i00] = a00; st[i01] = a01; st[i10] = a10; st[i11] = a11;
            __syncthreads();   // quads are disjoint per thread: one sync per pass
        }
        // CNOT block: one gather permutation
        const int* ip = iperm + l * DIM;
        int j0 = ip[t], j1 = ip[t + 256], j2 = ip[t + 512], j3 = ip[t + 768];
        float2 b0 = st[j0], b1 = st[j1], b2 = st[j2], b3 = st[j3];
        __syncthreads();       // all gathers done before overwrite
        st[t] = b0; st[t + 256] = b1; st[t + 512] = b2; st[t + 768] = b3;
        __syncthreads();
    }

    // ---- probs = clip(1024*|amp|^2, 0, 1) ----
    float* o = out + (size_t)n * DIM;
    #pragma unroll
    for (int k = 0; k < 4; ++k) {
        int i = t + k * 256;
        float2 a = st[i];
        float p = (a.x * a.x + a.y * a.y) * 1024.0f;
        o[i] = fminf(p, 1.0f);
    }
}

extern "C" void kernel_launch(void* const* d_in, const int* in_sizes, int n_in,
                              void* d_out, int out_size, void* d_ws, size_t ws_size,
                              hipStream_t stream) {
    const float* x = (const float*)d_in[0];     // (8192,1,32,32) fp32
    const float* w = (const float*)d_in[1];     // (16,10,3) fp32
    float* out   = (float*)d_out;               // (8192,1,32,32) fp32
    float* gates = (float*)d_ws;
    int*   iperm = (int*)((char*)d_ws + 160 * 8 * sizeof(float));

    prep_kernel<<<1, 1024, 0, stream>>>(w, gates, iperm);
    sim_kernel<<<8192, 256, 0, stream>>>(x, gates, iperm, out);
}

// Round 2
// 163.292 us; speedup vs baseline: 2.4504x; 2.4504x over previous
//
#include <hip/hip_runtime.h>
#include <math.h>

#define NW     10
#define DIM    1024
#define QDEPTH 16

typedef __attribute__((ext_vector_type(8))) _Float16 f16x8;
typedef __attribute__((ext_vector_type(4))) _Float16 f16x4;
typedef __attribute__((ext_vector_type(4))) float    f32x4;

// ---------------- ws layout ----------------
// gates : @0        (160 gates * 8 floats = 5120 B)
// iperm : @8192     (16*1024*4 = 64 KB)
// invs  : @81920    (8192*4 = 32 KB)
// Xh    : @1 MB     (8192*1024*2 = 16 MB)   f16 cast of x, row-major (B,K)
// B_il  : @18 MB    (2048*1024*2 = 4 MB)    f16, rows 2j=Re U[j,:], 2j+1=Im U[j,:]
#define WS_GATES 0
#define WS_IPERM 8192
#define WS_INVS  81920
#define WS_XH    (1u << 20)
#define WS_BIL   (18u << 20)

__device__ inline void gate2(const float* __restrict__ g, float2& p0, float2& p1) {
    float m00r = g[0], m00i = g[1], m01r = g[2], m01i = g[3];
    float m10r = g[4], m10i = g[5], m11r = g[6], m11i = g[7];
    float n0x = m00r*p0.x - m00i*p0.y + m01r*p1.x - m01i*p1.y;
    float n0y = m00r*p0.y + m00i*p0.x + m01r*p1.y + m01i*p1.x;
    float n1x = m10r*p0.x - m10i*p0.y + m11r*p1.x - m11i*p1.y;
    float n1y = m10r*p0.y + m10i*p0.x + m11r*p1.y + m11i*p1.x;
    p0 = make_float2(n0x, n0y);
    p1 = make_float2(n1x, n1y);
}

__global__ __launch_bounds__(1024)
void prep_kernel(const float* __restrict__ w, float* __restrict__ gates,
                 int* __restrict__ iperm) {
    int t = threadIdx.x;
    const float PI = 3.14159265358979323846f;
    if (t < QDEPTH * NW) {
        float phi   = tanhf(w[t*3 + 0]) * PI;
        float theta = tanhf(w[t*3 + 1]) * PI;
        float omega = tanhf(w[t*3 + 2]) * PI;
        float ch = cosf(theta * 0.5f), sh = sinf(theta * 0.5f);
        float ap = (phi + omega) * 0.5f;
        float am = (phi - omega) * 0.5f;
        float* g = gates + t * 8;
        g[0] =  cosf(ap) * ch;  g[1] = -sinf(ap) * ch;
        g[2] = -cosf(am) * sh;  g[3] = -sinf(am) * sh;
        g[4] =  cosf(am) * sh;  g[5] = -sinf(am) * sh;
        g[6] =  cosf(ap) * ch;  g[7] =  sinf(ap) * ch;
    }
    int v = t;
    for (int l = 0; l < QDEPTH; ++l) {
        int r = (l % (NW - 1)) + 1;
        int u = v;
        for (int wq = NW - 1; wq >= 0; --wq) {
            int bc = 9 - wq;
            int bt = 9 - ((wq + r) % NW);
            u ^= ((u >> bc) & 1) << bt;
        }
        iperm[l * DIM + v] = u;
    }
}

// Build U by simulating the 1024 basis states (verified round-1 simulator core).
// Block v computes column v of U and writes it into B_il (N,K layout, N=2j/2j+1).
__global__ __launch_bounds__(256)
void ubuild_kernel(const float* __restrict__ gates, const int* __restrict__ iperm,
                   _Float16* __restrict__ Bil) {
    __shared__ float2 st[DIM];
    const int v = blockIdx.x;
    const int t = threadIdx.x;

    #pragma unroll
    for (int k = 0; k < 4; ++k) {
        int i = t + k * 256;
        st[i] = make_float2(i == v ? 1.f : 0.f, 0.f);
    }
    __syncthreads();

    for (int l = 0; l < QDEPTH; ++l) {
        const float* gl = gates + l * NW * 8;
        #pragma unroll
        for (int pb = 4; pb >= 0; --pb) {
            const int b = 2 * pb;
            const float* gh = gl + (8 - b) * 8;
            const float* gm = gl + (9 - b) * 8;
            const int low = t & ((1 << b) - 1);
            const int i00 = ((t >> b) << (b + 2)) | low;
            const int i01 = i00 | (1 << b);
            const int i10 = i00 | (2 << b);
            const int i11 = i00 | (3 << b);
            float2 a00 = st[i00], a01 = st[i01], a10 = st[i10], a11 = st[i11];
            gate2(gh, a00, a10);
            gate2(gh, a01, a11);
            gate2(gm, a00, a01);
            gate2(gm, a10, a11);
            st[i00] = a00; st[i01] = a01; st[i10] = a10; st[i11] = a11;
            __syncthreads();
        }
        const int* ip = iperm + l * DIM;
        int j0 = ip[t], j1 = ip[t + 256], j2 = ip[t + 512], j3 = ip[t + 768];
        float2 b0 = st[j0], b1 = st[j1], b2 = st[j2], b3 = st[j3];
        __syncthreads();
        st[t] = b0; st[t + 256] = b1; st[t + 512] = b2; st[t + 768] = b3;
        __syncthreads();
    }

    #pragma unroll
    for (int k = 0; k < 4; ++k) {
        int i = t + k * 256;
        float2 a = st[i];
        Bil[(size_t)(2 * i)     * DIM + v] = (_Float16)a.x;
        Bil[(size_t)(2 * i + 1) * DIM + v] = (_Float16)a.y;
    }
}

// Per-row sumsq + f16 cast. One wave per batch row.
__global__ __launch_bounds__(64)
void normcast_kernel(const float* __restrict__ x, _Float16* __restrict__ Xh,
                     float* __restrict__ invs) {
    const int b = blockIdx.x;
    const int l = threadIdx.x;
    const float4* xr = (const float4*)(x + (size_t)b * DIM);
    float4 v[4];
    float ss = 0.f;
    #pragma unroll
    for (int c = 0; c < 4; ++c) {
        v[c] = xr[l + c * 64];
        ss += v[c].x*v[c].x + v[c].y*v[c].y + v[c].z*v[c].z + v[c].w*v[c].w;
    }
    #pragma unroll
    for (int o = 32; o >= 1; o >>= 1) ss += __shfl_down(ss, o, 64);
    ss = __shfl(ss, 0, 64);
    if (l == 0) invs[b] = 1024.0f / ss;
    f16x4* xo = (f16x4*)(Xh + (size_t)b * DIM);
    #pragma unroll
    for (int c = 0; c < 4; ++c) {
        f16x4 h;
        h[0] = (_Float16)v[c].x; h[1] = (_Float16)v[c].y;
        h[2] = (_Float16)v[c].z; h[3] = (_Float16)v[c].w;
        xo[l + c * 64] = h;
    }
}

// C[b,n] = sum_k Xh[b,k] * Bil[n,k];  out[b, n>>1] = clip(invs[b]*(c_even^2+c_odd^2), 0, 1)
// M=8192, N=2048, K=1024. 128x128 tile, BK=32, 4 waves (2x2), 4x4 16x16x32 frags/wave.
#define BM 128
#define BN 128
#define BK 32

__global__ __launch_bounds__(256)
void gemm_kernel(const _Float16* __restrict__ A, const _Float16* __restrict__ B,
                 const float* __restrict__ invs, float* __restrict__ out) {
    __shared__ _Float16 As[BM * BK];   // 8 KB, row-major [128][32]
    __shared__ _Float16 Bs[BN * BK];   // 8 KB
    const int t    = threadIdx.x;
    const int lane = t & 63;
    const int wid  = t >> 6;
    const int wm = wid >> 1, wn = wid & 1;
    const int m0 = blockIdx.y * BM;
    const int n0 = blockIdx.x * BN;

    // staging: thread t -> row t>>2 (and +64), 16B chunk (t&3)*8 elems
    const int srow   = t >> 2;
    const int schunk = (t & 3) * 8;
    const _Float16* Ag = A + (size_t)(m0 + srow) * 1024 + schunk;
    const _Float16* Bg = B + (size_t)(n0 + srow) * 1024 + schunk;

    f32x4 acc[4][4];
    const f32x4 zero = {0.f, 0.f, 0.f, 0.f};
    #pragma unroll
    for (int i = 0; i < 4; ++i)
        #pragma unroll
        for (int j = 0; j < 4; ++j) acc[i][j] = zero;

    const int fr = lane & 15;
    const int fk = (lane >> 4) * 8;

    for (int kt = 0; kt < 1024; kt += BK) {
        __syncthreads();
        __builtin_amdgcn_global_load_lds(
            (const __attribute__((address_space(1))) void*)(Ag + kt),
            (__attribute__((address_space(3))) void*)(As + t * 8), 16, 0, 0);
        __builtin_amdgcn_global_load_lds(
            (const __attribute__((address_space(1))) void*)(Ag + kt + 64 * 1024),
            (__attribute__((address_space(3))) void*)(As + 2048 + t * 8), 16, 0, 0);
        __builtin_amdgcn_global_load_lds(
            (const __attribute__((address_space(1))) void*)(Bg + kt),
            (__attribute__((address_space(3))) void*)(Bs + t * 8), 16, 0, 0);
        __builtin_amdgcn_global_load_lds(
            (const __attribute__((address_space(1))) void*)(Bg + kt + 64 * 1024),
            (__attribute__((address_space(3))) void*)(Bs + 2048 + t * 8), 16, 0, 0);
        __syncthreads();

        f16x8 af[4], bf[4];
        #pragma unroll
        for (int mf = 0; mf < 4; ++mf)
            af[mf] = *(const f16x8*)(As + (wm * 64 + mf * 16 + fr) * BK + fk);
        #pragma unroll
        for (int nf = 0; nf < 4; ++nf)
            bf[nf] = *(const f16x8*)(Bs + (wn * 64 + nf * 16 + fr) * BK + fk);
        #pragma unroll
        for (int mf = 0; mf < 4; ++mf)
            #pragma unroll
            for (int nf = 0; nf < 4; ++nf)
                acc[mf][nf] = __builtin_amdgcn_mfma_f32_16x16x32_f16(
                    af[mf], bf[nf], acc[mf][nf], 0, 0, 0);
    }

    // epilogue: C row = m0+wm*64+mf*16+(lane>>4)*4+r ; col = n0+wn*64+nf*16+(lane&15)
    const int colf = lane & 15;
    const int rowf = (lane >> 4) * 4;
    #pragma unroll
    for (int mf = 0; mf < 4; ++mf) {
        #pragma unroll
        for (int nf = 0; nf < 4; ++nf) {
            const int n = n0 + wn * 64 + nf * 16 + colf;
            #pragma unroll
            for (int r = 0; r < 4; ++r) {
                const int row = m0 + wm * 64 + mf * 16 + rowf + r;
                float vv = acc[mf][nf][r];
                float sq = vv * vv;
                float other = __shfl_xor(sq, 1, 64);
                if (!(lane & 1)) {
                    float p = fminf((sq + other) * invs[row], 1.0f);
                    out[(size_t)row * DIM + (n >> 1)] = p;
                }
            }
        }
    }
}

extern "C" void kernel_launch(void* const* d_in, const int* in_sizes, int n_in,
                              void* d_out, int out_size, void* d_ws, size_t ws_size,
                              hipStream_t stream) {
    const float* x = (const float*)d_in[0];     // (8192,1,32,32) fp32
    const float* w = (const float*)d_in[1];     // (16,10,3) fp32
    float* out = (float*)d_out;                 // (8192,1,32,32) fp32

    char* ws = (char*)d_ws;
    float*     gates = (float*)(ws + WS_GATES);
    int*       iperm = (int*)(ws + WS_IPERM);
    float*     invs  = (float*)(ws + WS_INVS);
    _Float16*  Xh    = (_Float16*)(ws + WS_XH);
    _Float16*  Bil   = (_Float16*)(ws + WS_BIL);

    prep_kernel<<<1, 1024, 0, stream>>>(w, gates, iperm);
    normcast_kernel<<<8192, 64, 0, stream>>>(x, Xh, invs);
    ubuild_kernel<<<1024, 256, 0, stream>>>(gates, iperm, Bil);
    gemm_kernel<<<dim3(16, 64), 256, 0, stream>>>(Xh, Bil, invs, out);
}